// Round 5
// baseline (153.502 us; speedup 1.0000x reference)
//
#include <hip/hip_runtime.h>
#include <math.h>

#define BATCH 64
#define DIM   640
#define MSP   100        // spatial M = 10*10
#define TILE  64
#define NT    10         // DIM / TILE
#define NPAIR 55         // NT*(NT+1)/2 upper-tri tile pairs
#define PTRI  205120     // DIM*(DIM+1)/2
#define KP    128        // K padded to multiple of 32 for MFMA
#define EPSV  1e-5f

// ws float-region offsets (floats)
#define WS_D 0
#define WS_S 40960
#define WS_G 81920            // 64 grand accumulators
// byte offset of bf16 xb (float region ends at 81984*4 = 327936, 256B-aligned)
#define XB_OFF 327936ull      // 64*640*128 shorts = 10,485,760 B; total ws ~10.8 MB

typedef __attribute__((ext_vector_type(8))) short short8;
typedef __attribute__((ext_vector_type(4))) float f32x4;

__device__ __forceinline__ short f2bf(float f) {
    union { float f; unsigned u; } x; x.f = f;
    unsigned r = x.u + 0x7fffu + ((x.u >> 16) & 1u);
    return (short)(r >> 16);
}
__device__ __forceinline__ float bf2f(short h) {
    union { unsigned u; float f; } x; x.u = ((unsigned)(unsigned short)h) << 16;
    return x.f;
}

// One pass over x: bf16-convert (RNE), pad K 100->128 with zeros, store xb;
// norms from the ROUNDED values (so diag d_i+d_i-2*G_ii cancels exactly vs the
// bf16 MFMA Gram); zero the S and G accumulators (ws is poisoned each call).
__global__ __launch_bounds__(256) void k_prep(const float* __restrict__ x,
                                              float* __restrict__ ws) {
    short* xb = (short*)((char*)ws + XB_OFF);
    const int t = threadIdx.x;
    const int rr = t >> 4, c = t & 15;
    const int row = blockIdx.x * 16 + rr;          // 0..40959
    const int k0 = c * 8;
    const float* src = x + (size_t)row * MSP;

    float v[8];
#pragma unroll
    for (int e = 0; e < 8; ++e) v[e] = 0.f;
    if (k0 <= 88) {                                // k0..k0+7 all < 100
        float4 u0 = *(const float4*)(src + k0);
        float4 u1 = *(const float4*)(src + k0 + 4);
        v[0] = u0.x; v[1] = u0.y; v[2] = u0.z; v[3] = u0.w;
        v[4] = u1.x; v[5] = u1.y; v[6] = u1.z; v[7] = u1.w;
    } else if (k0 == 96) {                         // only 96..99 valid (no OOB read)
        float4 u0 = *(const float4*)(src + 96);
        v[0] = u0.x; v[1] = u0.y; v[2] = u0.z; v[3] = u0.w;
    }

    short8 h; float s = 0.f;
#pragma unroll
    for (int e = 0; e < 8; ++e) {
        short hb = f2bf(v[e]);
        float vr = bf2f(hb);
        s += vr * vr;
        h[e] = hb;
    }
    *(short8*)(xb + (size_t)row * KP + k0) = h;

    s += __shfl_xor(s, 1); s += __shfl_xor(s, 2);
    s += __shfl_xor(s, 4); s += __shfl_xor(s, 8);
    if (c == 0) { ws[WS_D + row] = s; ws[WS_S + row] = 0.f; }
    if (blockIdx.x == 0 && t < BATCH) ws[WS_G + t] = 0.f;
}

__device__ __forceinline__ void decode_pair(int u, int& ti, int& tj) {
    ti = 0;
    while (u >= NT - ti) { u -= NT - ti; ++ti; }
    tj = ti + u;
}

// LDS-free Gram fragments: for X*X^T both A and B frags are row-segments of xb.
// Lane (lq,lm): A row = i0+r0+16a+lm, B row = j0+c0+16b+lm, k = ks*32+lq*8.
// Each global dwordx4 load covers 16 rows x 64B fully dense -> coalescing-clean.
// C/D: col = lane&15, row = (lane>>4)*4 + reg.
#define GRAM_MFMA_GLOBAL(acc)                                                   \
    {                                                                           \
        const short* aRow = xb + ((size_t)(b * DIM + i0 + r0 + lm)) * KP;       \
        const short* bRow = xb + ((size_t)(b * DIM + j0 + c0 + lm)) * KP;       \
        const int koff = lq * 8;                                                \
        short8 af[2][4], bf[2][4];                                              \
        _Pragma("unroll")                                                       \
        for (int ks = 0; ks < 4; ++ks) {                                        \
            af[0][ks] = *(const short8*)(aRow + ks * 32 + koff);                \
            af[1][ks] = *(const short8*)(aRow + 16 * KP + ks * 32 + koff);      \
            bf[0][ks] = *(const short8*)(bRow + ks * 32 + koff);                \
            bf[1][ks] = *(const short8*)(bRow + 16 * KP + ks * 32 + koff);      \
        }                                                                       \
        _Pragma("unroll")                                                       \
        for (int ks = 0; ks < 4; ++ks) {                                        \
            acc[0][0] = __builtin_amdgcn_mfma_f32_16x16x32_bf16(af[0][ks], bf[0][ks], acc[0][0], 0, 0, 0); \
            acc[0][1] = __builtin_amdgcn_mfma_f32_16x16x32_bf16(af[0][ks], bf[1][ks], acc[0][1], 0, 0, 0); \
            acc[1][0] = __builtin_amdgcn_mfma_f32_16x16x32_bf16(af[1][ks], bf[0][ks], acc[1][0], 0, 0, 0); \
            acc[1][1] = __builtin_amdgcn_mfma_f32_16x16x32_bf16(af[1][ks], bf[1][ks], acc[1][1], 0, 0, 0); \
        }                                                                       \
    }

// GEMM pass 1: Gram tile -> sqrt-dcov -> row/col sums S + per-batch grand.
__global__ __launch_bounds__(256) void k_sums(const float* __restrict__ tsc,
                                              float* __restrict__ ws) {
    __shared__ float sRow[TILE];
    __shared__ float sCol[TILE];

    int ti, tj;
    decode_pair(blockIdx.x, ti, tj);
    const int b = blockIdx.y;
    const int i0 = ti * TILE, j0 = tj * TILE;
    const int tid = threadIdx.x;
    const short* xb = (const short*)((const char*)ws + XB_OFF);

    if (tid < TILE) { sRow[tid] = 0.f; sCol[tid] = 0.f; }

    const int wave = tid >> 6, lane = tid & 63;
    const int lm = lane & 15, lq = lane >> 4;
    const int r0 = (wave >> 1) * 32, c0 = (wave & 1) * 32;

    f32x4 acc[2][2] = {};
    GRAM_MFMA_GLOBAL(acc)

    const float scale = expf(tsc[0]);
    const float* dn = ws + WS_D + b * DIM;
    float di[2][4], dj[2];
#pragma unroll
    for (int a = 0; a < 2; ++a)
#pragma unroll
        for (int r = 0; r < 4; ++r) di[a][r] = dn[i0 + r0 + 16 * a + lq * 4 + r];
#pragma unroll
    for (int bb = 0; bb < 2; ++bb) dj[bb] = dn[j0 + c0 + 16 * bb + lm];

    float rp[2][4] = {}, cp[2] = {};
#pragma unroll
    for (int a = 0; a < 2; ++a)
#pragma unroll
        for (int bb = 0; bb < 2; ++bb)
#pragma unroll
            for (int r = 0; r < 4; ++r) {
                float v = sqrtf(scale * fmaxf(di[a][r] + dj[bb] - 2.f * acc[a][bb][r], 0.f) + EPSV);
                rp[a][r] += v; cp[bb] += v;
            }

    __syncthreads();   // sRow/sCol zeroed before atomics
#pragma unroll
    for (int a = 0; a < 2; ++a)
#pragma unroll
        for (int r = 0; r < 4; ++r) {
            float v = rp[a][r];
            v += __shfl_xor(v, 1); v += __shfl_xor(v, 2);
            v += __shfl_xor(v, 4); v += __shfl_xor(v, 8);
            if (lm == 0) atomicAdd(&sRow[r0 + 16 * a + lq * 4 + r], v);
        }
#pragma unroll
    for (int bb = 0; bb < 2; ++bb) {
        float v = cp[bb];
        v += __shfl_xor(v, 16); v += __shfl_xor(v, 32);
        if (lq == 0) atomicAdd(&sCol[c0 + 16 * bb + lm], v);
    }
    __syncthreads();

    float* S = ws + WS_S + b * DIM;
    if (tid < TILE) {
        atomicAdd(&S[i0 + tid], sRow[tid]);
        if (ti != tj) atomicAdd(&S[j0 + tid], sCol[tid]);  // symmetry: col==row sums
        // grand total: sum of this tile; wave 0 butterfly, one atomic per block
        float g = sRow[tid];
        g += __shfl_xor(g, 1);  g += __shfl_xor(g, 2);  g += __shfl_xor(g, 4);
        g += __shfl_xor(g, 8);  g += __shfl_xor(g, 16); g += __shfl_xor(g, 32);
        if (tid == 0) atomicAdd(&ws[WS_G + b], (ti == tj ? 1.f : 2.f) * g);
    }
}

// GEMM pass 2 (recompute, LDS-free; xb is L2/L3-warm): centering + triu stores.
__global__ __launch_bounds__(256) void k_out(const float* __restrict__ tsc,
                                             const float* __restrict__ ws,
                                             float* __restrict__ out) {
    int ti, tj;
    decode_pair(blockIdx.x, ti, tj);
    const int b = blockIdx.y;
    const int i0 = ti * TILE, j0 = tj * TILE;
    const int tid = threadIdx.x;
    const short* xb = (const short*)((const char*)ws + XB_OFF);

    const int wave = tid >> 6, lane = tid & 63;
    const int lm = lane & 15, lq = lane >> 4;
    const int r0 = (wave >> 1) * 32, c0 = (wave & 1) * 32;

    f32x4 acc[2][2] = {};
    GRAM_MFMA_GLOBAL(acc)

    const float scale = expf(tsc[0]);
    const float inv = 1.f / (float)DIM;
    const float* dn = ws + WS_D + b * DIM;
    const float* S  = ws + WS_S + b * DIM;
    const float g = ws[WS_G + b] * (1.f / ((float)DIM * (float)DIM));
    const bool diag = (ti == tj);

    float di[2][4], si[2][4], dj[2], sj[2];
#pragma unroll
    for (int a = 0; a < 2; ++a)
#pragma unroll
        for (int r = 0; r < 4; ++r) {
            int i = i0 + r0 + 16 * a + lq * 4 + r;
            di[a][r] = dn[i]; si[a][r] = S[i] * inv;
        }
#pragma unroll
    for (int bb = 0; bb < 2; ++bb) {
        int j = j0 + c0 + 16 * bb + lm;
        dj[bb] = dn[j]; sj[bb] = S[j] * inv;
    }

    float* outb = out + (size_t)b * PTRI;
#pragma unroll
    for (int a = 0; a < 2; ++a)
#pragma unroll
        for (int r = 0; r < 4; ++r) {
            const int i = i0 + r0 + 16 * a + lq * 4 + r;
            const int base = i * DIM - (i * (i - 1)) / 2 - i;   // triu row offset minus i
#pragma unroll
            for (int bb = 0; bb < 2; ++bb) {
                const int j = j0 + c0 + 16 * bb + lm;
                if (!diag || j >= i) {
                    float v = sqrtf(scale * fmaxf(di[a][r] + dj[bb] - 2.f * acc[a][bb][r], 0.f) + EPSV);
                    outb[base + j] = v - si[a][r] - sj[bb] + g;
                }
            }
        }
}

extern "C" void kernel_launch(void* const* d_in, const int* in_sizes, int n_in,
                              void* d_out, int out_size, void* d_ws, size_t ws_size,
                              hipStream_t stream) {
    const float* x = (const float*)d_in[0];
    const float* t = (const float*)d_in[1];
    float* out = (float*)d_out;
    float* ws  = (float*)d_ws;   // needs ~10.8 MB (see layout at top)

    k_prep<<<dim3(BATCH * DIM / 16), 256, 0, stream>>>(x, ws);
    k_sums<<<dim3(NPAIR, BATCH),     256, 0, stream>>>(t, ws);
    k_out <<<dim3(NPAIR, BATCH),     256, 0, stream>>>(t, ws, out);
}

// Round 7
// 130.506 us; speedup vs baseline: 1.1762x; 1.1762x over previous
//
#include <hip/hip_runtime.h>
#include <math.h>

#define BATCH 64
#define DIM   640
#define MSP   100        // spatial M = 10*10
#define TILE  64
#define NT    10         // DIM / TILE
#define NPAIR 55         // NT*(NT+1)/2 upper-tri tile pairs
#define PTRI  205120     // DIM*(DIM+1)/2
#define EPSV  1e-5f

// ws float-region offsets (floats)
#define WS_D 0
#define WS_S 40960
#define WS_G 81920            // 64 grand accumulators (raw sums)
// byte offsets (float region ends at 81984*4 = 327936, 256B-aligned)
#define XB_OFF 327936ull      // swizzled bf16 x: 2560 panels x 2048 shorts = 10,485,760 B
#define TI_OFF 10813696ull    // fp16 dcov tiles (frag order): 3520 x 8192 B = 28,835,840 B
// total ws ~39.6 MB

// xb swizzle: panel = 16 rows x 128 k, stored [c = ks*4+lq][lm = row%16][8 halves].
// A gram wave's frag load (lanes lq=lane>>4, lm=lane&15) then reads ONE
// contiguous 1024B block -> fully coalesced, no LDS staging needed (fixes R5's
// 16-segment address divergence).

typedef __attribute__((ext_vector_type(8))) short short8;
typedef __attribute__((ext_vector_type(4))) float f32x4;
typedef __attribute__((ext_vector_type(2))) __fp16 fp16x2;   // cvt_pkrtz result type

__device__ __forceinline__ short f2bf(float f) {
    union { float f; unsigned u; } x; x.f = f;
    unsigned r = x.u + 0x7fffu + ((x.u >> 16) & 1u);
    return (short)(r >> 16);
}
__device__ __forceinline__ float bf2f(short h) {
    union { unsigned u; float f; } x; x.u = ((unsigned)(unsigned short)h) << 16;
    return x.f;
}

__device__ __forceinline__ void decode_pair(int u, int& ti, int& tj) {
    ti = 0;
    while (u >= NT - ti) { u -= NT - ti; ++ti; }
    tj = ti + u;
}

// One pass over x: bf16 RNE convert, K 100->128 zero-pad, store SWIZZLED xb;
// norms from ROUNDED values (diag d_i+d_i-2G_ii cancels exactly vs bf16 MFMA);
// zero S and G accumulators (ws is poisoned each call).
__global__ __launch_bounds__(256) void k_prep(const float* __restrict__ x,
                                              float* __restrict__ ws) {
    short* xb = (short*)((char*)ws + XB_OFF);
    const int t = threadIdx.x;
    const int rr = t >> 4, c = t & 15;             // rr = row-in-panel, c = k-chunk
    const int row = blockIdx.x * 16 + rr;          // 0..40959
    const int k0 = c * 8;
    const float* src = x + (size_t)row * MSP;

    float v[8];
#pragma unroll
    for (int e = 0; e < 8; ++e) v[e] = 0.f;
    if (k0 <= 88) {                                // k0..k0+7 all < 100
        float4 u0 = *(const float4*)(src + k0);
        float4 u1 = *(const float4*)(src + k0 + 4);
        v[0] = u0.x; v[1] = u0.y; v[2] = u0.z; v[3] = u0.w;
        v[4] = u1.x; v[5] = u1.y; v[6] = u1.z; v[7] = u1.w;
    } else if (k0 == 96) {                         // only 96..99 valid (no OOB read)
        float4 u0 = *(const float4*)(src + 96);
        v[0] = u0.x; v[1] = u0.y; v[2] = u0.z; v[3] = u0.w;
    }

    short8 h; float s = 0.f;
#pragma unroll
    for (int e = 0; e < 8; ++e) {
        short hb = f2bf(v[e]);
        float vr = bf2f(hb);
        s += vr * vr;
        h[e] = hb;
    }
    // swizzled store: panel base + c*128 + rr*8
    *(short8*)(xb + (size_t)blockIdx.x * 2048 + c * 128 + rr * 8) = h;

    // norm reduce over the 16 k-chunks (lanes with same rr, c = lane&15)
    s += __shfl_xor(s, 1); s += __shfl_xor(s, 2);
    s += __shfl_xor(s, 4); s += __shfl_xor(s, 8);
    if (c == 0) { ws[WS_D + row] = s; ws[WS_S + row] = 0.f; }
    if (blockIdx.x == 0 && t < BATCH) ws[WS_G + t] = 0.f;
}

// Single GEMM pass, LDS-free: swizzled-global frag loads -> 2x2 MFMA quadrant
// per wave -> sqrt-dcov -> fp16 tile store (frag order) + S/grand reductions.
__global__ __launch_bounds__(256) void k_gram(const float* __restrict__ tsc,
                                              float* __restrict__ ws) {
    __shared__ float sRow[TILE];
    __shared__ float sCol[TILE];

    int ti, tj;
    decode_pair(blockIdx.x, ti, tj);
    const int b = blockIdx.y;
    const int i0 = ti * TILE, j0 = tj * TILE;
    const int tid = threadIdx.x;
    const short* xb = (const short*)((const char*)ws + XB_OFF);

    if (tid < TILE) { sRow[tid] = 0.f; sCol[tid] = 0.f; }

    const int wave = tid >> 6, lane = tid & 63;
    const int lm = lane & 15, lq = lane >> 4;
    const int r0 = (wave >> 1) * 32, c0 = (wave & 1) * 32;

    // per-lane frag pointers into swizzled xb (each wave-load = 1024B dense)
    const short* pa = xb + (size_t)(b * 40 + ((i0 + r0) >> 4)) * 2048 + lq * 128 + lm * 8;
    const short* pb = xb + (size_t)(b * 40 + ((j0 + c0) >> 4)) * 2048 + lq * 128 + lm * 8;

    f32x4 acc[2][2] = {};
#pragma unroll
    for (int ks = 0; ks < 4; ++ks) {
        short8 a0 = *(const short8*)(pa + ks * 512);
        short8 a1 = *(const short8*)(pa + 2048 + ks * 512);
        short8 b0 = *(const short8*)(pb + ks * 512);
        short8 b1 = *(const short8*)(pb + 2048 + ks * 512);
        acc[0][0] = __builtin_amdgcn_mfma_f32_16x16x32_bf16(a0, b0, acc[0][0], 0, 0, 0);
        acc[0][1] = __builtin_amdgcn_mfma_f32_16x16x32_bf16(a0, b1, acc[0][1], 0, 0, 0);
        acc[1][0] = __builtin_amdgcn_mfma_f32_16x16x32_bf16(a1, b0, acc[1][0], 0, 0, 0);
        acc[1][1] = __builtin_amdgcn_mfma_f32_16x16x32_bf16(a1, b1, acc[1][1], 0, 0, 0);
    }

    const float scale = expf(tsc[0]);
    const float* dn = ws + WS_D + b * DIM;
    float di[2][4], dj[2];
#pragma unroll
    for (int a = 0; a < 2; ++a)
#pragma unroll
        for (int r = 0; r < 4; ++r) di[a][r] = dn[i0 + r0 + 16 * a + lq * 4 + r];
#pragma unroll
    for (int bb = 0; bb < 2; ++bb) dj[bb] = dn[j0 + c0 + 16 * bb + lm];

    float rp[2][4] = {}, cp[2] = {};
    short* tb = (short*)((char*)ws + TI_OFF) + ((size_t)(b * NPAIR + blockIdx.x) << 12);
    uint4 st[2];
#pragma unroll
    for (int a = 0; a < 2; ++a) {
        unsigned wd[4];
#pragma unroll
        for (int bb = 0; bb < 2; ++bb)
#pragma unroll
            for (int p = 0; p < 2; ++p) {
                float d0 = di[a][2 * p]     + dj[bb];
                float d1 = di[a][2 * p + 1] + dj[bb];
                float v0 = __builtin_amdgcn_sqrtf(
                    fmaf(scale, fmaxf(fmaf(-2.f, acc[a][bb][2 * p],     d0), 0.f), EPSV));
                float v1 = __builtin_amdgcn_sqrtf(
                    fmaf(scale, fmaxf(fmaf(-2.f, acc[a][bb][2 * p + 1], d1), 0.f), EPSV));
                rp[a][2 * p] += v0; rp[a][2 * p + 1] += v1; cp[bb] += v0 + v1;
                union { fp16x2 h; unsigned u; } cv;
                cv.h = __builtin_amdgcn_cvt_pkrtz(v0, v1);
                wd[bb * 2 + p] = cv.u;
            }
        st[a].x = wd[0]; st[a].y = wd[1]; st[a].z = wd[2]; st[a].w = wd[3];
    }
    // lane's 16 halves = 32B contiguous; wave = 2KB contiguous store
    *(uint4*)(tb + tid * 16)     = st[0];
    *(uint4*)(tb + tid * 16 + 8) = st[1];

    __syncthreads();   // sRow/sCol zero-init visible before LDS atomics
#pragma unroll
    for (int a = 0; a < 2; ++a)
#pragma unroll
        for (int r = 0; r < 4; ++r) {
            float v = rp[a][r];
            v += __shfl_xor(v, 1); v += __shfl_xor(v, 2);
            v += __shfl_xor(v, 4); v += __shfl_xor(v, 8);
            if (lm == 0) atomicAdd(&sRow[r0 + 16 * a + lq * 4 + r], v);
        }
#pragma unroll
    for (int bb = 0; bb < 2; ++bb) {
        float v = cp[bb];
        v += __shfl_xor(v, 16); v += __shfl_xor(v, 32);
        if (lq == 0) atomicAdd(&sCol[c0 + 16 * bb + lm], v);
    }
    __syncthreads();

    float* S = ws + WS_S + b * DIM;
    if (tid < TILE) {
        atomicAdd(&S[i0 + tid], sRow[tid]);
        if (ti != tj) atomicAdd(&S[j0 + tid], sCol[tid]);  // symmetry: col==row sums
        float gg = sRow[tid];                              // per-batch grand (raw)
        gg += __shfl_xor(gg, 1);  gg += __shfl_xor(gg, 2);  gg += __shfl_xor(gg, 4);
        gg += __shfl_xor(gg, 8);  gg += __shfl_xor(gg, 16); gg += __shfl_xor(gg, 32);
        if (tid == 0) atomicAdd(&ws[WS_G + b], (ti == tj ? 1.f : 2.f) * gg);
    }
}

// Streaming final: read fp16 tiles in frag order (32B/thread contiguous),
// apply centering, write triu fp32 (4x64B segments per store instr).
__global__ __launch_bounds__(256) void k_final(const float* __restrict__ ws,
                                               float* __restrict__ out) {
    int ti, tj;
    decode_pair(blockIdx.x, ti, tj);
    const int b = blockIdx.y;
    const int i0 = ti * TILE, j0 = tj * TILE;
    const int tid = threadIdx.x;
    const int wave = tid >> 6, lane = tid & 63;
    const int lm = lane & 15, lq = lane >> 4;
    const int r0 = (wave >> 1) * 32, c0 = (wave & 1) * 32;

    const uint4* tb = (const uint4*)((const char*)ws + TI_OFF +
                                     ((size_t)(b * NPAIR + blockIdx.x) << 13));
    uint4 u[2];
    u[0] = tb[tid * 2]; u[1] = tb[tid * 2 + 1];

    const float inv = 1.f / (float)DIM;
    const float g = ws[WS_G + b] * (inv * inv);
    const float* S = ws + WS_S + b * DIM;

    float ai[2][4]; int ib[2][4];
#pragma unroll
    for (int a = 0; a < 2; ++a)
#pragma unroll
        for (int r = 0; r < 4; ++r) {
            int i = i0 + r0 + 16 * a + 4 * lq + r;
            ai[a][r] = g - S[i] * inv;
            ib[a][r] = i * DIM - (i * (i - 1)) / 2 - i;   // triu row offset minus i
        }
    float bj[2]; int jj[2];
#pragma unroll
    for (int bb = 0; bb < 2; ++bb) {
        int j = j0 + c0 + 16 * bb + lm;
        jj[bb] = j; bj[bb] = -S[j] * inv;
    }

    const bool offd = (ti != tj);
    float* outb = out + (size_t)b * PTRI;
#pragma unroll
    for (int a = 0; a < 2; ++a) {
        unsigned wd[4] = {u[a].x, u[a].y, u[a].z, u[a].w};
        const int ibase = i0 + r0 + 16 * a + 4 * lq;
#pragma unroll
        for (int bb = 0; bb < 2; ++bb)
#pragma unroll
            for (int p = 0; p < 2; ++p) {
                union { unsigned u; fp16x2 h; } cv; cv.u = wd[bb * 2 + p];
                float v0 = (float)cv.h.x, v1 = (float)cv.h.y;
                const int r = 2 * p;
                if (offd || jj[bb] >= ibase + r)
                    outb[ib[a][r] + jj[bb]] = v0 + ai[a][r] + bj[bb];
                if (offd || jj[bb] >= ibase + r + 1)
                    outb[ib[a][r + 1] + jj[bb]] = v1 + ai[a][r + 1] + bj[bb];
            }
    }
}

extern "C" void kernel_launch(void* const* d_in, const int* in_sizes, int n_in,
                              void* d_out, int out_size, void* d_ws, size_t ws_size,
                              hipStream_t stream) {
    const float* x = (const float*)d_in[0];
    const float* t = (const float*)d_in[1];
    float* out = (float*)d_out;
    float* ws  = (float*)d_ws;   // needs ~39.6 MB (see layout at top)

    k_prep <<<dim3(BATCH * DIM / 16), 256, 0, stream>>>(x, ws);
    k_gram <<<dim3(NPAIR, BATCH),     256, 0, stream>>>(t, ws);
    k_final<<<dim3(NPAIR, BATCH),     256, 0, stream>>>(ws, out);
}